// Round 6
// baseline (724.832 us; speedup 1.0000x reference)
//
#include <hip/hip_runtime.h>
#include <hip/hip_bf16.h>

#define NN 20000
#define EE 320000
#define LGN 4

typedef unsigned short u16;
typedef short bf16x8 __attribute__((ext_vector_type(8)));
typedef float f32x4 __attribute__((ext_vector_type(4)));

__device__ __forceinline__ float bf2f(u16 v) {
    unsigned int u = ((unsigned int)v) << 16;
    float f; __builtin_memcpy(&f, &u, 4); return f;
}
__device__ __forceinline__ u16 f2bf(float f) {
    __hip_bfloat16 h = __float2bfloat16(f);
    u16 u; __builtin_memcpy(&u, &h, 2); return u;
}

// ---- pass 1: degree (by source), col histogram, ew copy-out ----
__global__ __launch_bounds__(256) void k_edge1(const int* __restrict__ ei,
                                               const float* __restrict__ ew,
                                               float* __restrict__ deg,
                                               int* __restrict__ counts,
                                               float* __restrict__ out_ew) {
    int e = blockIdx.x * 256 + threadIdx.x;
    if (e >= EE) return;
    int r = ei[e];
    float w = ew[e];
    atomicAdd(&deg[r], w);
    atomicAdd(&counts[ei[EE + e]], 1);
    out_ew[e] = w;
}

__global__ __launch_bounds__(256) void k_rsqrt(float* __restrict__ deg) {
    int i = blockIdx.x * 256 + threadIdx.x;
    if (i >= NN) return;
    float d = deg[i];
    deg[i] = (d > 0.f) ? rsqrtf(d) : 0.f;
}

// ---- exclusive scan of col histogram (single block) ----
__global__ __launch_bounds__(1024) void k_scan(const int* __restrict__ counts,
                                               int* __restrict__ offs) {
    __shared__ int part[1024];
    int t = threadIdx.x;
    const int C = (NN + 1023) / 1024;  // 20
    int lo = t * C, hi = min(lo + C, NN);
    int s = 0;
    for (int i = lo; i < hi; i++) s += counts[i];
    part[t] = s;
    __syncthreads();
    for (int off = 1; off < 1024; off <<= 1) {
        int add = (t >= off) ? part[t - off] : 0;
        __syncthreads();
        part[t] += add;
        __syncthreads();
    }
    int base = part[t] - s;
    for (int i = lo; i < hi; i++) { offs[i] = base; base += counts[i]; }
    if (t == 1023) offs[NN] = part[1023];
}

// ---- pass 2: compute norm, scatter (row, norm) int2 into CSR slots ----
__global__ __launch_bounds__(256) void k_scatter(const int* __restrict__ ei,
                                                 const float* __restrict__ ew,
                                                 const float* __restrict__ dis,
                                                 const int* __restrict__ offs,
                                                 int* __restrict__ cursor,
                                                 int2* __restrict__ nbrs) {
    int e = blockIdx.x * 256 + threadIdx.x;
    if (e >= EE) return;
    int r = ei[e], c = ei[EE + e];
    float nm = -(dis[r] * ew[e] * dis[c]);
    int pidx = offs[c] + atomicAdd(&cursor[c], 1);
    nbrs[pidx] = make_int2(r, __float_as_int(nm));
}

// ---- f32 -> bf16 cast (no transpose) ----
__global__ __launch_bounds__(256) void k_cast(const float* __restrict__ src,
                                              u16* __restrict__ dst, int n) {
    int i = blockIdx.x * 256 + threadIdx.x;
    if (i < n) dst[i] = f2bf(src[i]);
}

// ---- f32 [K][256] -> bf16 [256][K] transpose-cast (weights) ----
__global__ __launch_bounds__(256) void k_cast_T(const float* __restrict__ src,
                                                u16* __restrict__ dst, int K) {
    __shared__ u16 tile[32][33];
    int kt = blockIdx.x * 32, nt = blockIdx.y * 32;
    int tx = threadIdx.x & 31, ty = threadIdx.x >> 5;  // 32 x 8
#pragma unroll
    for (int i = 0; i < 32; i += 8)
        tile[ty + i][tx] = f2bf(src[(size_t)(kt + ty + i) * 256 + (nt + tx)]);
    __syncthreads();
#pragma unroll
    for (int i = 0; i < 32; i += 8)
        dst[(size_t)(nt + ty + i) * K + (kt + tx)] = tile[tx][ty + i];
}

// ---- fold BN affine: s = gamma*rsqrt(var+eps), t = beta - mean*s ----
__global__ __launch_bounds__(256) void k_foldbn(const float* __restrict__ g,
                                                const float* __restrict__ be,
                                                const float* __restrict__ mn,
                                                const float* __restrict__ vr,
                                                float* __restrict__ sc,
                                                float* __restrict__ sh) {
    int t = threadIdx.x;
    if (t < 256) {
        float s = g[t] * rsqrtf(vr[t] + 1e-5f);
        sc[t] = s;
        sh[t] = be[t] - mn[t] * s;
    }
}

// ---- CSR SpMM: one WAVE per node, no LDS, no barriers, 8 gathers in flight ----
__global__ __launch_bounds__(256) void k_prop(const u16* __restrict__ x, int ldx,
                                              const u16* __restrict__ xsub, int ldsub,
                                              int dotx2,
                                              u16* __restrict__ out, int ldo,
                                              const int* __restrict__ offs,
                                              const int2* __restrict__ nbrs) {
    int c = __builtin_amdgcn_readfirstlane(blockIdx.x * 4 + (threadIdx.x >> 6));
    int lane = threadIdx.x & 63;
    int s = offs[c], e = offs[c + 1];
    float a0 = 0.f, a1 = 0.f, a2 = 0.f, a3 = 0.f;
    for (int i = s; i < e; i += 8) {
        int2 mm[8];
        ushort4 xv[8];
#pragma unroll
        for (int j = 0; j < 8; j++) mm[j] = nbrs[i + j];
#pragma unroll
        for (int j = 0; j < 8; j++)
            xv[j] = *(const ushort4*)(x + (size_t)mm[j].x * ldx + lane * 4);
#pragma unroll
        for (int j = 0; j < 8; j++) {
            float w = (i + j < e) ? __int_as_float(mm[j].y) : 0.f;
            a0 += w * bf2f(xv[j].x);
            a1 += w * bf2f(xv[j].y);
            a2 += w * bf2f(xv[j].z);
            a3 += w * bf2f(xv[j].w);
        }
    }
    if (dotx2) {
        ushort4 xs = *(const ushort4*)(xsub + (size_t)c * ldsub + lane * 4);
        a0 = 2.f * a0 - bf2f(xs.x);
        a1 = 2.f * a1 - bf2f(xs.y);
        a2 = 2.f * a2 - bf2f(xs.z);
        a3 = 2.f * a3 - bf2f(xs.w);
    }
    ushort4 o;
    o.x = f2bf(a0); o.y = f2bf(a1); o.z = f2bf(a2); o.w = f2bf(a3);
    *(ushort4*)(out + (size_t)c * ldo + lane * 4) = o;
}

// ---- bf16 MFMA GEMM, no-LDS K-loop, LIGHT waves. ----
// One wave = 16 rows x 64 cols x full K: acc[4] (16 VGPR) + B dbuf 4+4 frags
// (32 VGPR) + A frags (16 VGPR) ~ 80 VGPR total -> no spills, pipeline intact.
// Grid (NN/16, 4) = 5000 waves (~4.9/SIMD) for TLP. Fragments load directly
// from global in MFMA layout; B is L2-resident; each 16-row strip reads B once
// across its 4 waves. NN % 16 == 0 -> no row guards.
// mode 0: relu -> bf16 outb (ldob) via per-wave LDS transpose.
// mode 1: +bias, relu, BN affine, @w2 (+b2 on by==0) -> atomicAdd f32 logits.
__global__ __launch_bounds__(64, 2) void k_gemm(
    const u16* __restrict__ A0, const u16* __restrict__ A1,
    const u16* __restrict__ A2, const u16* __restrict__ A3,
    int lda0, int lda1, int lda2, int lda3,
    int K, const u16* __restrict__ Bt,
    int mode,
    u16* __restrict__ outb, int ldob,
    const float* __restrict__ bias, const float* __restrict__ sc,
    const float* __restrict__ sh,
    const float* __restrict__ w2, const float* __restrict__ b2,
    float* __restrict__ outlog) {
    int l = threadIdx.x;
    int q = l >> 4, l16 = l & 15;
    int m0 = blockIdx.x * 16;
    int n0 = blockIdx.y * 64;
    int arow = m0 + l16;

    f32x4 acc[4] = {};

    auto loadA = [&](int kt) -> bf16x8 {
        int ch = kt >> 8;  // wave-uniform -> SGPR select
        const u16* ap;
        int la;
        if (ch == 0) { ap = A0; la = lda0; }
        else if (ch == 1) { ap = A1; la = lda1; }
        else if (ch == 2) { ap = A2; la = lda2; }
        else { ap = A3; la = lda3; }
        return *(const bf16x8*)(ap + (size_t)arow * la + (kt & 255) + q * 8);
    };
    const u16* bbase = Bt + (size_t)(n0 + l16) * K + q * 8;
    auto loadB = [&](int nt, int kt) -> bf16x8 {
        return *(const bf16x8*)(bbase + (size_t)nt * 16 * K + kt);
    };

    bf16x8 a_cur = loadA(0);
    bf16x8 a_nxt = loadA(32);  // K >= 64 always
    bf16x8 bb0[4], bb1[4];
#pragma unroll
    for (int nt = 0; nt < 4; nt++) bb0[nt] = loadB(nt, 0);

    for (int kt = 0; kt < K; kt += 64) {
        // prefetch B for kt+32, A for kt+64 (overlap MFMAs on bb0)
#pragma unroll
        for (int nt = 0; nt < 4; nt++) bb1[nt] = loadB(nt, kt + 32);
        bf16x8 a2 = (kt + 64 < K) ? loadA(kt + 64) : bf16x8{};
#pragma unroll
        for (int nt = 0; nt < 4; nt++)
            acc[nt] = __builtin_amdgcn_mfma_f32_16x16x32_bf16(a_cur, bb0[nt], acc[nt], 0, 0, 0);
        // prefetch B for kt+64, A for kt+96 (overlap MFMAs on bb1)
        if (kt + 64 < K) {
#pragma unroll
            for (int nt = 0; nt < 4; nt++) bb0[nt] = loadB(nt, kt + 64);
        }
        bf16x8 a3 = (kt + 96 < K) ? loadA(kt + 96) : bf16x8{};
#pragma unroll
        for (int nt = 0; nt < 4; nt++)
            acc[nt] = __builtin_amdgcn_mfma_f32_16x16x32_bf16(a_nxt, bb1[nt], acc[nt], 0, 0, 0);
        a_cur = a2;
        a_nxt = a3;
    }

    if (mode == 0) {
        __shared__ __align__(16) u16 Cs[16 * 72 + 8];
#pragma unroll
        for (int nt = 0; nt < 4; nt++)
#pragma unroll
            for (int i = 0; i < 4; i++) {
                float v = acc[nt][i];
                v = v > 0.f ? v : 0.f;
                Cs[(q * 4 + i) * 72 + nt * 16 + l16] = f2bf(v);
            }
        // single wave: compiler orders ds_write->ds_read via lgkmcnt
        int r = l >> 2, cb = (l & 3) * 16;
#pragma unroll
        for (int j = 0; j < 2; j++) {
            uint4 cv = *(const uint4*)&Cs[r * 72 + cb + j * 8];
            *(uint4*)(outb + (size_t)(m0 + r) * ldob + n0 + cb + j * 8) = cv;
        }
    } else {
        float bi[4], s4[4], h4[4], wa[4], wb[4];
#pragma unroll
        for (int nt = 0; nt < 4; nt++) {
            int col = n0 + nt * 16 + l16;
            bi[nt] = bias[col];
            s4[nt] = sc[col];
            h4[nt] = sh[col];
            wa[nt] = w2[2 * col];
            wb[nt] = w2[2 * col + 1];
        }
        float b20 = b2[0], b21 = b2[1];
#pragma unroll
        for (int i = 0; i < 4; i++) {
            float p0 = 0.f, p1 = 0.f;
#pragma unroll
            for (int nt = 0; nt < 4; nt++) {
                float v = acc[nt][i] + bi[nt];
                v = v > 0.f ? v : 0.f;
                v = v * s4[nt] + h4[nt];
                p0 += v * wa[nt];
                p1 += v * wb[nt];
            }
#pragma unroll
            for (int off = 1; off < 16; off <<= 1) {
                p0 += __shfl_xor(p0, off, 64);
                p1 += __shfl_xor(p1, off, 64);
            }
            if (l16 == 0) {
                int row = m0 + q * 4 + i;
                float add0 = p0, add1 = p1;
                if (blockIdx.y == 0) { add0 += b20; add1 += b21; }
                atomicAdd(&outlog[row * 2 + 0], add0);
                atomicAdd(&outlog[row * 2 + 1], add1);
            }
        }
    }
}

extern "C" void kernel_launch(void* const* d_in, const int* in_sizes, int n_in,
                              void* d_out, int out_size, void* d_ws, size_t ws_size,
                              hipStream_t stream) {
    const float* features = (const float*)d_in[0];
    const int* ei = (const int*)d_in[1];
    // d_in[2] = edgenet_input (bypassed by edge_weight_override)
    const float* ew = (const float*)d_in[3];
    const float* cheb_w = (const float*)d_in[4];
    const float* w1 = (const float*)d_in[5];
    const float* b1 = (const float*)d_in[6];
    const float* g = (const float*)d_in[7];
    const float* be = (const float*)d_in[8];
    const float* mn = (const float*)d_in[9];
    const float* vr = (const float*)d_in[10];
    const float* w2 = (const float*)d_in[11];
    const float* b2 = (const float*)d_in[12];
    float* out = (float*)d_out;  // [NN*2] logits, then [EE] ew

    char* p = (char*)d_ws;
    auto alloc = [&](size_t bytes) -> char* {
        char* r = p;
        p += (bytes + 255) & ~(size_t)255;
        return r;
    };
    float* deg = (float*)alloc((size_t)NN * 4);
    int* counts = (int*)alloc((size_t)(NN + 1) * 4);
    int* cursor = (int*)alloc((size_t)NN * 4);
    size_t zero_bytes = (size_t)(p - (char*)deg);
    int* offs = (int*)alloc((size_t)(NN + 1) * 4);
    int2* nbrs = (int2*)alloc((size_t)(EE + 8) * 8);
    u16* xb = (u16*)alloc((size_t)NN * 256 * 2);
    u16* tx1 = (u16*)alloc((size_t)NN * 256 * 2);
    u16* tx2 = (u16*)alloc((size_t)NN * 256 * 2);
    u16* jk = (u16*)alloc((size_t)NN * 1024 * 2);
    u16* chebT = (u16*)alloc((size_t)LGN * 3 * 256 * 256 * 2);  // per layer [256][768]
    u16* w1T = (u16*)alloc((size_t)1024 * 256 * 2);             // [256][1024]
    float* sc = (float*)alloc(256 * 4);
    float* sh = (float*)alloc(256 * 4);

    hipMemsetAsync(deg, 0, zero_bytes, stream);
    hipMemsetAsync(nbrs + EE, 0, 8 * sizeof(int2), stream);  // safe overrun pad
    hipMemsetAsync(out, 0, (size_t)NN * 2 * 4, stream);      // logits accumulated atomically
    k_edge1<<<(EE + 255) / 256, 256, 0, stream>>>(ei, ew, deg, counts, out + (size_t)NN * 2);
    k_rsqrt<<<(NN + 255) / 256, 256, 0, stream>>>(deg);
    k_scan<<<1, 1024, 0, stream>>>(counts, offs);
    k_scatter<<<(EE + 255) / 256, 256, 0, stream>>>(ei, ew, deg, offs, cursor, nbrs);
    k_cast<<<((NN * 256) + 255) / 256, 256, 0, stream>>>(features, xb, NN * 256);
    for (int i = 0; i < LGN; i++)
        k_cast_T<<<dim3(24, 8), 256, 0, stream>>>(cheb_w + (size_t)i * 768 * 256,
                                                  chebT + (size_t)i * 256 * 768, 768);
    k_cast_T<<<dim3(32, 8), 256, 0, stream>>>(w1, w1T, 1024);
    k_foldbn<<<1, 256, 0, stream>>>(g, be, mn, vr, sc, sh);

    const int gg = NN / 16;  // 1250, exact
    for (int i = 0; i < LGN; i++) {
        const u16* x = (i == 0) ? xb : (jk + (size_t)(i - 1) * 256);
        int ldx = (i == 0) ? 256 : 1024;
        k_prop<<<NN / 4, 256, 0, stream>>>(x, ldx, (const u16*)nullptr, 0, 0, tx1, 256, offs,
                                           nbrs);
        k_prop<<<NN / 4, 256, 0, stream>>>(tx1, 256, x, ldx, 1, tx2, 256, offs, nbrs);
        k_gemm<<<dim3(gg, 4), 64, 0, stream>>>(
            x, tx1, tx2, (const u16*)nullptr, ldx, 256, 256, 0, 768,
            chebT + (size_t)i * 256 * 768, 0, jk + (size_t)i * 256, 1024, (const float*)nullptr,
            (const float*)nullptr, (const float*)nullptr, (const float*)nullptr,
            (const float*)nullptr, (float*)nullptr);
    }
    k_gemm<<<dim3(gg, 4), 64, 0, stream>>>(jk, jk + 256, jk + 512, jk + 768, 1024, 1024, 1024,
                                           1024, 1024, w1T, 1, (u16*)nullptr, 0, b1, sc, sh, w2,
                                           b2, out);
}

// Round 7
// 680.762 us; speedup vs baseline: 1.0647x; 1.0647x over previous
//
#include <hip/hip_runtime.h>
#include <hip/hip_bf16.h>

#define NN 20000
#define EE 320000
#define LGN 4

typedef unsigned short u16;
typedef short bf16x8 __attribute__((ext_vector_type(8)));
typedef float f32x4 __attribute__((ext_vector_type(4)));

__device__ __forceinline__ float bf2f(u16 v) {
    unsigned int u = ((unsigned int)v) << 16;
    float f; __builtin_memcpy(&f, &u, 4); return f;
}
__device__ __forceinline__ u16 f2bf(float f) {
    __hip_bfloat16 h = __float2bfloat16(f);
    u16 u; __builtin_memcpy(&u, &h, 2); return u;
}

// ---- pass 1: degree (by source), col histogram, ew copy-out ----
__global__ __launch_bounds__(256) void k_edge1(const int* __restrict__ ei,
                                               const float* __restrict__ ew,
                                               float* __restrict__ deg,
                                               int* __restrict__ counts,
                                               float* __restrict__ out_ew) {
    int e = blockIdx.x * 256 + threadIdx.x;
    if (e >= EE) return;
    int r = ei[e];
    float w = ew[e];
    atomicAdd(&deg[r], w);
    atomicAdd(&counts[ei[EE + e]], 1);
    out_ew[e] = w;
}

__global__ __launch_bounds__(256) void k_rsqrt(float* __restrict__ deg) {
    int i = blockIdx.x * 256 + threadIdx.x;
    if (i >= NN) return;
    float d = deg[i];
    deg[i] = (d > 0.f) ? rsqrtf(d) : 0.f;
}

// ---- exclusive scan of col histogram (single block) ----
__global__ __launch_bounds__(1024) void k_scan(const int* __restrict__ counts,
                                               int* __restrict__ offs) {
    __shared__ int part[1024];
    int t = threadIdx.x;
    const int C = (NN + 1023) / 1024;  // 20
    int lo = t * C, hi = min(lo + C, NN);
    int s = 0;
    for (int i = lo; i < hi; i++) s += counts[i];
    part[t] = s;
    __syncthreads();
    for (int off = 1; off < 1024; off <<= 1) {
        int add = (t >= off) ? part[t - off] : 0;
        __syncthreads();
        part[t] += add;
        __syncthreads();
    }
    int base = part[t] - s;
    for (int i = lo; i < hi; i++) { offs[i] = base; base += counts[i]; }
    if (t == 1023) offs[NN] = part[1023];
}

// ---- pass 2: compute norm, scatter (row, norm) int2 into CSR slots ----
__global__ __launch_bounds__(256) void k_scatter(const int* __restrict__ ei,
                                                 const float* __restrict__ ew,
                                                 const float* __restrict__ dis,
                                                 const int* __restrict__ offs,
                                                 int* __restrict__ cursor,
                                                 int2* __restrict__ nbrs) {
    int e = blockIdx.x * 256 + threadIdx.x;
    if (e >= EE) return;
    int r = ei[e], c = ei[EE + e];
    float nm = -(dis[r] * ew[e] * dis[c]);
    int pidx = offs[c] + atomicAdd(&cursor[c], 1);
    nbrs[pidx] = make_int2(r, __float_as_int(nm));
}

// ---- f32 -> bf16 cast (no transpose) ----
__global__ __launch_bounds__(256) void k_cast(const float* __restrict__ src,
                                              u16* __restrict__ dst, int n) {
    int i = blockIdx.x * 256 + threadIdx.x;
    if (i < n) dst[i] = f2bf(src[i]);
}

// ---- f32 [K][256] -> bf16 [256][K] transpose-cast (weights) ----
__global__ __launch_bounds__(256) void k_cast_T(const float* __restrict__ src,
                                                u16* __restrict__ dst, int K) {
    __shared__ u16 tile[32][33];
    int kt = blockIdx.x * 32, nt = blockIdx.y * 32;
    int tx = threadIdx.x & 31, ty = threadIdx.x >> 5;  // 32 x 8
#pragma unroll
    for (int i = 0; i < 32; i += 8)
        tile[ty + i][tx] = f2bf(src[(size_t)(kt + ty + i) * 256 + (nt + tx)]);
    __syncthreads();
#pragma unroll
    for (int i = 0; i < 32; i += 8)
        dst[(size_t)(nt + ty + i) * K + (kt + tx)] = tile[tx][ty + i];
}

// ---- fold BN affine: s = gamma*rsqrt(var+eps), t = beta - mean*s ----
__global__ __launch_bounds__(256) void k_foldbn(const float* __restrict__ g,
                                                const float* __restrict__ be,
                                                const float* __restrict__ mn,
                                                const float* __restrict__ vr,
                                                float* __restrict__ sc,
                                                float* __restrict__ sh) {
    int t = threadIdx.x;
    if (t < 256) {
        float s = g[t] * rsqrtf(vr[t] + 1e-5f);
        sc[t] = s;
        sh[t] = be[t] - mn[t] * s;
    }
}

// ---- CSR SpMM: one WAVE per node, no LDS, no barriers, 8 gathers in flight ----
__global__ __launch_bounds__(256) void k_prop(const u16* __restrict__ x, int ldx,
                                              const u16* __restrict__ xsub, int ldsub,
                                              int dotx2,
                                              u16* __restrict__ out, int ldo,
                                              const int* __restrict__ offs,
                                              const int2* __restrict__ nbrs) {
    int c = __builtin_amdgcn_readfirstlane(blockIdx.x * 4 + (threadIdx.x >> 6));
    int lane = threadIdx.x & 63;
    int s = offs[c], e = offs[c + 1];
    float a0 = 0.f, a1 = 0.f, a2 = 0.f, a3 = 0.f;
    for (int i = s; i < e; i += 8) {
        int2 mm[8];
        ushort4 xv[8];
#pragma unroll
        for (int j = 0; j < 8; j++) mm[j] = nbrs[i + j];
#pragma unroll
        for (int j = 0; j < 8; j++)
            xv[j] = *(const ushort4*)(x + (size_t)mm[j].x * ldx + lane * 4);
#pragma unroll
        for (int j = 0; j < 8; j++) {
            float w = (i + j < e) ? __int_as_float(mm[j].y) : 0.f;
            a0 += w * bf2f(xv[j].x);
            a1 += w * bf2f(xv[j].y);
            a2 += w * bf2f(xv[j].z);
            a3 += w * bf2f(xv[j].w);
        }
    }
    if (dotx2) {
        ushort4 xs = *(const ushort4*)(xsub + (size_t)c * ldsub + lane * 4);
        a0 = 2.f * a0 - bf2f(xs.x);
        a1 = 2.f * a1 - bf2f(xs.y);
        a2 = 2.f * a2 - bf2f(xs.z);
        a3 = 2.f * a3 - bf2f(xs.w);
    }
    ushort4 o;
    o.x = f2bf(a0); o.y = f2bf(a1); o.z = f2bf(a2); o.w = f2bf(a3);
    *(ushort4*)(out + (size_t)c * ldo + lane * 4) = o;
}

// ---- bf16 MFMA GEMM: A staged once to LDS, shared by 4 n-quarter waves. ----
// Block = 256 thr / 4 waves, tile 16 rows x 256 cols. A strip (16 x K) staged
// cooperatively into LDS in MFMA-fragment order (frag f = step*64+q*16+l16 at
// f*16B) -> K-loop ds_read_b128 at base+lane*16 = contiguous, conflict-free.
// One barrier total; K-loop: 1 ds_read + 4 L2-resident B loads (dbuf) + 4 MFMA.
// A HBM traffic = read once. Grid NN/16 = 1250 blocks; LDS 32 KB -> 5 blk/CU.
// mode 0: relu -> bf16 outb (ldob) via per-wave LDS transpose (reuses A LDS).
// mode 1: +bias, relu, BN affine, @w2 -> LDS cross-wave reduce -> f32 logits.
__global__ __launch_bounds__(256, 4) void k_gemm(
    const u16* __restrict__ A0, const u16* __restrict__ A1,
    const u16* __restrict__ A2, const u16* __restrict__ A3,
    int lda0, int lda1, int lda2, int lda3,
    int K, const u16* __restrict__ Bt,
    int mode,
    u16* __restrict__ outb, int ldob,
    const float* __restrict__ bias, const float* __restrict__ sc,
    const float* __restrict__ sh,
    const float* __restrict__ w2, const float* __restrict__ b2,
    float* __restrict__ outlog) {
    __shared__ __align__(16) u16 Alds[16384];  // 32 KB: K/32*64 frags * 8 shorts
    int t = threadIdx.x;
    int wv = t >> 6, l = t & 63;
    int q = l >> 4, l16 = l & 15;
    int m0 = blockIdx.x * 16;
    int n0 = wv * 64;
    const int steps = K >> 5;

    // ---- stage A strip into LDS in fragment order ----
    {
        int sl16 = t & 15, sq = (t >> 4) & 3, st0 = t >> 6;  // st0 wave-uniform
        for (int s = st0; s < steps; s += 4) {
            int kg = s * 32;  // wave-uniform
            int ch = kg >> 8;
            const u16* ap;
            int la;
            if (ch == 0) { ap = A0; la = lda0; }
            else if (ch == 1) { ap = A1; la = lda1; }
            else if (ch == 2) { ap = A2; la = lda2; }
            else { ap = A3; la = lda3; }
            uint4 v = *(const uint4*)(ap + (size_t)(m0 + sl16) * la + (kg & 255) + sq * 8);
            *(uint4*)&Alds[(s * 64 + sq * 16 + sl16) * 8] = v;
        }
    }
    __syncthreads();

    f32x4 acc[4] = {};
    const u16* bbase = Bt + (size_t)(n0 + l16) * K + q * 8;
    auto loadB = [&](int nt, int kt) -> bf16x8 {
        return *(const bf16x8*)(bbase + (size_t)nt * 16 * K + kt);
    };

    bf16x8 bb0[4], bb1[4];
#pragma unroll
    for (int nt = 0; nt < 4; nt++) bb0[nt] = loadB(nt, 0);

    for (int s = 0; s < steps; s += 2) {  // steps even (24 or 32)
#pragma unroll
        for (int nt = 0; nt < 4; nt++) bb1[nt] = loadB(nt, (s + 1) * 32);
        bf16x8 a0 = *(const bf16x8*)&Alds[(s * 64 + l) * 8];
#pragma unroll
        for (int nt = 0; nt < 4; nt++)
            acc[nt] = __builtin_amdgcn_mfma_f32_16x16x32_bf16(a0, bb0[nt], acc[nt], 0, 0, 0);
        if (s + 2 < steps) {
#pragma unroll
            for (int nt = 0; nt < 4; nt++) bb0[nt] = loadB(nt, (s + 2) * 32);
        }
        bf16x8 a1 = *(const bf16x8*)&Alds[((s + 1) * 64 + l) * 8];
#pragma unroll
        for (int nt = 0; nt < 4; nt++)
            acc[nt] = __builtin_amdgcn_mfma_f32_16x16x32_bf16(a1, bb1[nt], acc[nt], 0, 0, 0);
    }

    if (mode == 0) {
        __syncthreads();  // all waves done with A region
        u16* Cs = Alds + wv * 1160;  // [16][72] +8 pad, per-wave region (2320 B)
#pragma unroll
        for (int nt = 0; nt < 4; nt++)
#pragma unroll
            for (int i = 0; i < 4; i++) {
                float v = acc[nt][i];
                v = v > 0.f ? v : 0.f;
                Cs[(q * 4 + i) * 72 + nt * 16 + l16] = f2bf(v);
            }
        // same-wave ds_write->ds_read ordered via lgkmcnt
        int r = l >> 2, cb = (l & 3) * 16;
#pragma unroll
        for (int j = 0; j < 2; j++) {
            uint4 cv = *(const uint4*)&Cs[r * 72 + cb + j * 8];
            *(uint4*)(outb + (size_t)(m0 + r) * ldob + n0 + cb + j * 8) = cv;
        }
    } else {
        float bi[4], s4[4], h4[4], wa[4], wb[4];
#pragma unroll
        for (int nt = 0; nt < 4; nt++) {
            int col = n0 + nt * 16 + l16;
            bi[nt] = bias[col];
            s4[nt] = sc[col];
            h4[nt] = sh[col];
            wa[nt] = w2[2 * col];
            wb[nt] = w2[2 * col + 1];
        }
        __syncthreads();  // done with A region; reuse as reduction buffer
        float* red = (float*)Alds;  // [4][16][2]
#pragma unroll
        for (int i = 0; i < 4; i++) {
            float p0 = 0.f, p1 = 0.f;
#pragma unroll
            for (int nt = 0; nt < 4; nt++) {
                float v = acc[nt][i] + bi[nt];
                v = v > 0.f ? v : 0.f;
                v = v * s4[nt] + h4[nt];
                p0 += v * wa[nt];
                p1 += v * wb[nt];
            }
#pragma unroll
            for (int off = 1; off < 16; off <<= 1) {
                p0 += __shfl_xor(p0, off, 64);
                p1 += __shfl_xor(p1, off, 64);
            }
            if (l16 == 0) {
                int row = q * 4 + i;
                red[(wv * 16 + row) * 2 + 0] = p0;
                red[(wv * 16 + row) * 2 + 1] = p1;
            }
        }
        __syncthreads();
        if (t < 32) {
            int row = t >> 1, cp = t & 1;
            float v = red[(0 * 16 + row) * 2 + cp] + red[(1 * 16 + row) * 2 + cp] +
                      red[(2 * 16 + row) * 2 + cp] + red[(3 * 16 + row) * 2 + cp];
            outlog[(size_t)(m0 + row) * 2 + cp] = v + b2[cp];
        }
    }
}

extern "C" void kernel_launch(void* const* d_in, const int* in_sizes, int n_in,
                              void* d_out, int out_size, void* d_ws, size_t ws_size,
                              hipStream_t stream) {
    const float* features = (const float*)d_in[0];
    const int* ei = (const int*)d_in[1];
    // d_in[2] = edgenet_input (bypassed by edge_weight_override)
    const float* ew = (const float*)d_in[3];
    const float* cheb_w = (const float*)d_in[4];
    const float* w1 = (const float*)d_in[5];
    const float* b1 = (const float*)d_in[6];
    const float* g = (const float*)d_in[7];
    const float* be = (const float*)d_in[8];
    const float* mn = (const float*)d_in[9];
    const float* vr = (const float*)d_in[10];
    const float* w2 = (const float*)d_in[11];
    const float* b2 = (const float*)d_in[12];
    float* out = (float*)d_out;  // [NN*2] logits, then [EE] ew

    char* p = (char*)d_ws;
    auto alloc = [&](size_t bytes) -> char* {
        char* r = p;
        p += (bytes + 255) & ~(size_t)255;
        return r;
    };
    float* deg = (float*)alloc((size_t)NN * 4);
    int* counts = (int*)alloc((size_t)(NN + 1) * 4);
    int* cursor = (int*)alloc((size_t)NN * 4);
    size_t zero_bytes = (size_t)(p - (char*)deg);
    int* offs = (int*)alloc((size_t)(NN + 1) * 4);
    int2* nbrs = (int2*)alloc((size_t)(EE + 8) * 8);
    u16* xb = (u16*)alloc((size_t)NN * 256 * 2);
    u16* tx1 = (u16*)alloc((size_t)NN * 256 * 2);
    u16* tx2 = (u16*)alloc((size_t)NN * 256 * 2);
    u16* jk = (u16*)alloc((size_t)NN * 1024 * 2);
    u16* chebT = (u16*)alloc((size_t)LGN * 3 * 256 * 256 * 2);  // per layer [256][768]
    u16* w1T = (u16*)alloc((size_t)1024 * 256 * 2);             // [256][1024]
    float* sc = (float*)alloc(256 * 4);
    float* sh = (float*)alloc(256 * 4);

    hipMemsetAsync(deg, 0, zero_bytes, stream);
    hipMemsetAsync(nbrs + EE, 0, 8 * sizeof(int2), stream);  // safe overrun pad
    k_edge1<<<(EE + 255) / 256, 256, 0, stream>>>(ei, ew, deg, counts, out + (size_t)NN * 2);
    k_rsqrt<<<(NN + 255) / 256, 256, 0, stream>>>(deg);
    k_scan<<<1, 1024, 0, stream>>>(counts, offs);
    k_scatter<<<(EE + 255) / 256, 256, 0, stream>>>(ei, ew, deg, offs, cursor, nbrs);
    k_cast<<<((NN * 256) + 255) / 256, 256, 0, stream>>>(features, xb, NN * 256);
    for (int i = 0; i < LGN; i++)
        k_cast_T<<<dim3(24, 8), 256, 0, stream>>>(cheb_w + (size_t)i * 768 * 256,
                                                  chebT + (size_t)i * 256 * 768, 768);
    k_cast_T<<<dim3(32, 8), 256, 0, stream>>>(w1, w1T, 1024);
    k_foldbn<<<1, 256, 0, stream>>>(g, be, mn, vr, sc, sh);

    const int gg = NN / 16;  // 1250, exact
    for (int i = 0; i < LGN; i++) {
        const u16* x = (i == 0) ? xb : (jk + (size_t)(i - 1) * 256);
        int ldx = (i == 0) ? 256 : 1024;
        k_prop<<<NN / 4, 256, 0, stream>>>(x, ldx, (const u16*)nullptr, 0, 0, tx1, 256, offs,
                                           nbrs);
        k_prop<<<NN / 4, 256, 0, stream>>>(tx1, 256, x, ldx, 1, tx2, 256, offs, nbrs);
        k_gemm<<<gg, 256, 0, stream>>>(
            x, tx1, tx2, (const u16*)nullptr, ldx, 256, 256, 0, 768,
            chebT + (size_t)i * 256 * 768, 0, jk + (size_t)i * 256, 1024, (const float*)nullptr,
            (const float*)nullptr, (const float*)nullptr, (const float*)nullptr,
            (const float*)nullptr, (float*)nullptr);
    }
    k_gemm<<<gg, 256, 0, stream>>>(jk, jk + 256, jk + 512, jk + 768, 1024, 1024, 1024, 1024,
                                   1024, w1T, 1, (u16*)nullptr, 0, b1, sc, sh, w2, b2, out);
}

// Round 8
// 582.784 us; speedup vs baseline: 1.2437x; 1.1681x over previous
//
#include <hip/hip_runtime.h>
#include <hip/hip_bf16.h>

#define NN 20000
#define EE 320000
#define LGN 4

typedef unsigned short u16;
typedef short bf16x8 __attribute__((ext_vector_type(8)));
typedef float f32x4 __attribute__((ext_vector_type(4)));

__device__ __forceinline__ float bf2f(u16 v) {
    unsigned int u = ((unsigned int)v) << 16;
    float f; __builtin_memcpy(&f, &u, 4); return f;
}
__device__ __forceinline__ u16 f2bf(float f) {
    __hip_bfloat16 h = __float2bfloat16(f);
    u16 u; __builtin_memcpy(&u, &h, 2); return u;
}

// async global->LDS, 16B per lane, LDS dest = wave-uniform base + lane*16
__device__ __forceinline__ void gll16(const void* g, void* l) {
    __builtin_amdgcn_global_load_lds(
        (const __attribute__((address_space(1))) unsigned int*)g,
        (__attribute__((address_space(3))) unsigned int*)l, 16, 0, 0);
}

// ---- pass 1: degree (by source), col histogram, ew copy-out ----
__global__ __launch_bounds__(256) void k_edge1(const int* __restrict__ ei,
                                               const float* __restrict__ ew,
                                               float* __restrict__ deg,
                                               int* __restrict__ counts,
                                               float* __restrict__ out_ew) {
    int e = blockIdx.x * 256 + threadIdx.x;
    if (e >= EE) return;
    int r = ei[e];
    float w = ew[e];
    atomicAdd(&deg[r], w);
    atomicAdd(&counts[ei[EE + e]], 1);
    out_ew[e] = w;
}

__global__ __launch_bounds__(256) void k_rsqrt(float* __restrict__ deg) {
    int i = blockIdx.x * 256 + threadIdx.x;
    if (i >= NN) return;
    float d = deg[i];
    deg[i] = (d > 0.f) ? rsqrtf(d) : 0.f;
}

// ---- exclusive scan of col histogram (single block) ----
__global__ __launch_bounds__(1024) void k_scan(const int* __restrict__ counts,
                                               int* __restrict__ offs) {
    __shared__ int part[1024];
    int t = threadIdx.x;
    const int C = (NN + 1023) / 1024;  // 20
    int lo = t * C, hi = min(lo + C, NN);
    int s = 0;
    for (int i = lo; i < hi; i++) s += counts[i];
    part[t] = s;
    __syncthreads();
    for (int off = 1; off < 1024; off <<= 1) {
        int add = (t >= off) ? part[t - off] : 0;
        __syncthreads();
        part[t] += add;
        __syncthreads();
    }
    int base = part[t] - s;
    for (int i = lo; i < hi; i++) { offs[i] = base; base += counts[i]; }
    if (t == 1023) offs[NN] = part[1023];
}

// ---- pass 2: compute norm, scatter (row, norm) int2 into CSR slots ----
__global__ __launch_bounds__(256) void k_scatter(const int* __restrict__ ei,
                                                 const float* __restrict__ ew,
                                                 const float* __restrict__ dis,
                                                 const int* __restrict__ offs,
                                                 int* __restrict__ cursor,
                                                 int2* __restrict__ nbrs) {
    int e = blockIdx.x * 256 + threadIdx.x;
    if (e >= EE) return;
    int r = ei[e], c = ei[EE + e];
    float nm = -(dis[r] * ew[e] * dis[c]);
    int pidx = offs[c] + atomicAdd(&cursor[c], 1);
    nbrs[pidx] = make_int2(r, __float_as_int(nm));
}

// ---- f32 -> bf16 cast (no transpose) ----
__global__ __launch_bounds__(256) void k_cast(const float* __restrict__ src,
                                              u16* __restrict__ dst, int n) {
    int i = blockIdx.x * 256 + threadIdx.x;
    if (i < n) dst[i] = f2bf(src[i]);
}

// ---- f32 [K][256] -> bf16 [256][K] transpose-cast (weights) ----
__global__ __launch_bounds__(256) void k_cast_T(const float* __restrict__ src,
                                                u16* __restrict__ dst, int K) {
    __shared__ u16 tile[32][33];
    int kt = blockIdx.x * 32, nt = blockIdx.y * 32;
    int tx = threadIdx.x & 31, ty = threadIdx.x >> 5;  // 32 x 8
#pragma unroll
    for (int i = 0; i < 32; i += 8)
        tile[ty + i][tx] = f2bf(src[(size_t)(kt + ty + i) * 256 + (nt + tx)]);
    __syncthreads();
#pragma unroll
    for (int i = 0; i < 32; i += 8)
        dst[(size_t)(nt + ty + i) * K + (kt + tx)] = tile[tx][ty + i];
}

// ---- fold BN affine: s = gamma*rsqrt(var+eps), t = beta - mean*s ----
__global__ __launch_bounds__(256) void k_foldbn(const float* __restrict__ g,
                                                const float* __restrict__ be,
                                                const float* __restrict__ mn,
                                                const float* __restrict__ vr,
                                                float* __restrict__ sc,
                                                float* __restrict__ sh) {
    int t = threadIdx.x;
    if (t < 256) {
        float s = g[t] * rsqrtf(vr[t] + 1e-5f);
        sc[t] = s;
        sh[t] = be[t] - mn[t] * s;
    }
}

// ---- CSR SpMM: one WAVE per node, no LDS, no barriers, 8 gathers in flight ----
__global__ __launch_bounds__(256) void k_prop(const u16* __restrict__ x, int ldx,
                                              const u16* __restrict__ xsub, int ldsub,
                                              int dotx2,
                                              u16* __restrict__ out, int ldo,
                                              const int* __restrict__ offs,
                                              const int2* __restrict__ nbrs) {
    int c = __builtin_amdgcn_readfirstlane(blockIdx.x * 4 + (threadIdx.x >> 6));
    int lane = threadIdx.x & 63;
    int s = offs[c], e = offs[c + 1];
    float a0 = 0.f, a1 = 0.f, a2 = 0.f, a3 = 0.f;
    for (int i = s; i < e; i += 8) {
        int2 mm[8];
        ushort4 xv[8];
#pragma unroll
        for (int j = 0; j < 8; j++) mm[j] = nbrs[i + j];
#pragma unroll
        for (int j = 0; j < 8; j++)
            xv[j] = *(const ushort4*)(x + (size_t)mm[j].x * ldx + lane * 4);
#pragma unroll
        for (int j = 0; j < 8; j++) {
            float w = (i + j < e) ? __int_as_float(mm[j].y) : 0.f;
            a0 += w * bf2f(xv[j].x);
            a1 += w * bf2f(xv[j].y);
            a2 += w * bf2f(xv[j].z);
            a3 += w * bf2f(xv[j].w);
        }
    }
    if (dotx2) {
        ushort4 xs = *(const ushort4*)(xsub + (size_t)c * ldsub + lane * 4);
        a0 = 2.f * a0 - bf2f(xs.x);
        a1 = 2.f * a1 - bf2f(xs.y);
        a2 = 2.f * a2 - bf2f(xs.z);
        a3 = 2.f * a3 - bf2f(xs.w);
    }
    ushort4 o;
    o.x = f2bf(a0); o.y = f2bf(a1); o.z = f2bf(a2); o.w = f2bf(a3);
    *(ushort4*)(out + (size_t)c * ldo + lane * 4) = o;
}

// ---- bf16 MFMA GEMM, m97-style global_load_lds double-buffered K-loop. ----
// Block 256 thr / 4 waves, tile M=32 x N=256 (wave = 32 rows x 64 cols).
// Per 32-k step: 16 B-frags + 2 A-frags (18 KB) DMA'd to LDS in MFMA fragment
// order (lane*16B scatter == fragment layout); hardware-queued loads cannot be
// sunk by the allocator; drain = vmcnt(0)+barrier (proven m97 structure).
// Grid 625 (NN/32, exact). LDS 36 KB dbuf -> 4 blocks/CU cap.
// mode 0: relu -> bf16 outb (ldob) via per-wave LDS transpose.
// mode 1: +bias, relu, BN affine, @w2 -> LDS cross-wave reduce -> f32 logits.
__global__ __launch_bounds__(256, 4) void k_gemm(
    const u16* __restrict__ A0, const u16* __restrict__ A1,
    const u16* __restrict__ A2, const u16* __restrict__ A3,
    int lda0, int lda1, int lda2, int lda3,
    int K, const u16* __restrict__ Bt,
    int mode,
    u16* __restrict__ outb, int ldob,
    const float* __restrict__ bias, const float* __restrict__ sc,
    const float* __restrict__ sh,
    const float* __restrict__ w2, const float* __restrict__ b2,
    float* __restrict__ outlog) {
    __shared__ __align__(16) u16 lds[2 * 18 * 512];  // 2 bufs x 18 frags x 1KB
    int t = threadIdx.x;
    int wv = t >> 6, l = t & 63;
    int q = l >> 4, l16 = l & 15;
    int m0 = blockIdx.x * 32;  // NN % 32 == 0, no guards
    const int steps = K >> 5;

    f32x4 acc[2][4] = {};

    auto stage = [&](int buf, int s) {
        int kt = s * 32;
        u16* base = lds + buf * 18 * 512;
#pragma unroll
        for (int nt = 0; nt < 4; nt++) {
            const u16* g = Bt + (size_t)(wv * 64 + nt * 16 + l16) * K + kt + q * 8;
            gll16(g, base + (wv * 4 + nt) * 512);
        }
        if (wv < 2) {  // wave-uniform branch: waves 0,1 stage the two A-frags
            int ch = kt >> 8;  // wave-uniform -> SGPR select
            const u16* ap;
            int la;
            if (ch == 0) { ap = A0; la = lda0; }
            else if (ch == 1) { ap = A1; la = lda1; }
            else if (ch == 2) { ap = A2; la = lda2; }
            else { ap = A3; la = lda3; }
            const u16* g = ap + (size_t)(m0 + wv * 16 + l16) * la + (kt & 255) + q * 8;
            gll16(g, base + (16 + wv) * 512);
        }
    };

    stage(0, 0);
    for (int s = 0; s < steps; s++) {
        __syncthreads();  // vmcnt(0) drain of buf[s&1] loads + buf[(s+1)&1] free
        if (s + 1 < steps) stage((s + 1) & 1, s + 1);
        const u16* base = lds + (s & 1) * 18 * 512;
        bf16x8 a[2], b[4];
#pragma unroll
        for (int mh = 0; mh < 2; mh++)
            a[mh] = *(const bf16x8*)(base + (16 + mh) * 512 + l * 8);
#pragma unroll
        for (int nt = 0; nt < 4; nt++)
            b[nt] = *(const bf16x8*)(base + (wv * 4 + nt) * 512 + l * 8);
#pragma unroll
        for (int mh = 0; mh < 2; mh++)
#pragma unroll
            for (int nt = 0; nt < 4; nt++)
                acc[mh][nt] =
                    __builtin_amdgcn_mfma_f32_16x16x32_bf16(a[mh], b[nt], acc[mh][nt], 0, 0, 0);
    }
    __syncthreads();  // all waves done reading LDS; reuse below

    if (mode == 0) {
        u16* Cs = lds + wv * 2304;  // per-wave [32][72]
#pragma unroll
        for (int mh = 0; mh < 2; mh++)
#pragma unroll
            for (int nt = 0; nt < 4; nt++)
#pragma unroll
                for (int i = 0; i < 4; i++) {
                    float v = acc[mh][nt][i];
                    v = v > 0.f ? v : 0.f;
                    Cs[(mh * 16 + q * 4 + i) * 72 + nt * 16 + l16] = f2bf(v);
                }
        // same-wave ds_write->ds_read ordered via lgkmcnt
        int r = l >> 1, cb = (l & 1) * 32;
#pragma unroll
        for (int j = 0; j < 4; j++) {
            uint4 cv = *(const uint4*)&Cs[r * 72 + cb + j * 8];
            *(uint4*)(outb + (size_t)(m0 + r) * ldob + wv * 64 + cb + j * 8) = cv;
        }
    } else {
        float bi[4], s4[4], h4[4], wa[4], wb[4];
#pragma unroll
        for (int nt = 0; nt < 4; nt++) {
            int col = wv * 64 + nt * 16 + l16;
            bi[nt] = bias[col];
            s4[nt] = sc[col];
            h4[nt] = sh[col];
            wa[nt] = w2[2 * col];
            wb[nt] = w2[2 * col + 1];
        }
        float* red = (float*)lds;  // [4][32][2]
#pragma unroll
        for (int mh = 0; mh < 2; mh++)
#pragma unroll
            for (int i = 0; i < 4; i++) {
                float p0 = 0.f, p1 = 0.f;
#pragma unroll
                for (int nt = 0; nt < 4; nt++) {
                    float v = acc[mh][nt][i] + bi[nt];
                    v = v > 0.f ? v : 0.f;
                    v = v * s4[nt] + h4[nt];
                    p0 += v * wa[nt];
                    p1 += v * wb[nt];
                }
#pragma unroll
                for (int off = 1; off < 16; off <<= 1) {
                    p0 += __shfl_xor(p0, off, 64);
                    p1 += __shfl_xor(p1, off, 64);
                }
                if (l16 == 0) {
                    int row = mh * 16 + q * 4 + i;
                    red[(wv * 32 + row) * 2 + 0] = p0;
                    red[(wv * 32 + row) * 2 + 1] = p1;
                }
            }
        __syncthreads();
        if (t < 64) {
            int row = t >> 1, cp = t & 1;
            float v = red[(0 * 32 + row) * 2 + cp] + red[(1 * 32 + row) * 2 + cp] +
                      red[(2 * 32 + row) * 2 + cp] + red[(3 * 32 + row) * 2 + cp];
            outlog[(size_t)(m0 + row) * 2 + cp] = v + b2[cp];
        }
    }
}

extern "C" void kernel_launch(void* const* d_in, const int* in_sizes, int n_in,
                              void* d_out, int out_size, void* d_ws, size_t ws_size,
                              hipStream_t stream) {
    const float* features = (const float*)d_in[0];
    const int* ei = (const int*)d_in[1];
    // d_in[2] = edgenet_input (bypassed by edge_weight_override)
    const float* ew = (const float*)d_in[3];
    const float* cheb_w = (const float*)d_in[4];
    const float* w1 = (const float*)d_in[5];
    const float* b1 = (const float*)d_in[6];
    const float* g = (const float*)d_in[7];
    const float* be = (const float*)d_in[8];
    const float* mn = (const float*)d_in[9];
    const float* vr = (const float*)d_in[10];
    const float* w2 = (const float*)d_in[11];
    const float* b2 = (const float*)d_in[12];
    float* out = (float*)d_out;  // [NN*2] logits, then [EE] ew

    char* p = (char*)d_ws;
    auto alloc = [&](size_t bytes) -> char* {
        char* r = p;
        p += (bytes + 255) & ~(size_t)255;
        return r;
    };
    float* deg = (float*)alloc((size_t)NN * 4);
    int* counts = (int*)alloc((size_t)(NN + 1) * 4);
    int* cursor = (int*)alloc((size_t)NN * 4);
    size_t zero_bytes = (size_t)(p - (char*)deg);
    int* offs = (int*)alloc((size_t)(NN + 1) * 4);
    int2* nbrs = (int2*)alloc((size_t)(EE + 8) * 8);
    u16* xb = (u16*)alloc((size_t)NN * 256 * 2);
    u16* tx1 = (u16*)alloc((size_t)NN * 256 * 2);
    u16* tx2 = (u16*)alloc((size_t)NN * 256 * 2);
    u16* jk = (u16*)alloc((size_t)NN * 1024 * 2);
    u16* chebT = (u16*)alloc((size_t)LGN * 3 * 256 * 256 * 2);  // per layer [256][768]
    u16* w1T = (u16*)alloc((size_t)1024 * 256 * 2);             // [256][1024]
    float* sc = (float*)alloc(256 * 4);
    float* sh = (float*)alloc(256 * 4);

    hipMemsetAsync(deg, 0, zero_bytes, stream);
    hipMemsetAsync(nbrs + EE, 0, 8 * sizeof(int2), stream);  // safe overrun pad
    k_edge1<<<(EE + 255) / 256, 256, 0, stream>>>(ei, ew, deg, counts, out + (size_t)NN * 2);
    k_rsqrt<<<(NN + 255) / 256, 256, 0, stream>>>(deg);
    k_scan<<<1, 1024, 0, stream>>>(counts, offs);
    k_scatter<<<(EE + 255) / 256, 256, 0, stream>>>(ei, ew, deg, offs, cursor, nbrs);
    k_cast<<<((NN * 256) + 255) / 256, 256, 0, stream>>>(features, xb, NN * 256);
    for (int i = 0; i < LGN; i++)
        k_cast_T<<<dim3(24, 8), 256, 0, stream>>>(cheb_w + (size_t)i * 768 * 256,
                                                  chebT + (size_t)i * 256 * 768, 768);
    k_cast_T<<<dim3(32, 8), 256, 0, stream>>>(w1, w1T, 1024);
    k_foldbn<<<1, 256, 0, stream>>>(g, be, mn, vr, sc, sh);

    const int gg = NN / 32;  // 625, exact
    for (int i = 0; i < LGN; i++) {
        const u16* x = (i == 0) ? xb : (jk + (size_t)(i - 1) * 256);
        int ldx = (i == 0) ? 256 : 1024;
        k_prop<<<NN / 4, 256, 0, stream>>>(x, ldx, (const u16*)nullptr, 0, 0, tx1, 256, offs,
                                           nbrs);
        k_prop<<<NN / 4, 256, 0, stream>>>(tx1, 256, x, ldx, 1, tx2, 256, offs, nbrs);
        k_gemm<<<gg, 256, 0, stream>>>(
            x, tx1, tx2, (const u16*)nullptr, ldx, 256, 256, 0, 768,
            chebT + (size_t)i * 256 * 768, 0, jk + (size_t)i * 256, 1024, (const float*)nullptr,
            (const float*)nullptr, (const float*)nullptr, (const float*)nullptr,
            (const float*)nullptr, (float*)nullptr);
    }
    k_gemm<<<gg, 256, 0, stream>>>(jk, jk + 256, jk + 512, jk + 768, 1024, 1024, 1024, 1024,
                                   1024, w1T, 1, (u16*)nullptr, 0, b1, sc, sh, w2, b2, out);
}